// Round 19
// baseline (38.294 us; speedup 1.0000x reference)
//
#include <hip/hip_runtime.h>
#include <hip/hip_bf16.h>

// Problem constants
#define BATCH   8192
#define NGRP    8
#define MAXGS   64
#define DMODEL  2048
#define TM      16
#define NBLK    32                // histogram/scatter blocks
#define NKK     (DMODEL / 32)     // 64 K-chunks
#define MAXTILES 520              // sum ceil(cnt/16) <= 512 + 7

typedef __attribute__((ext_vector_type(8))) short  short8;
typedef __attribute__((ext_vector_type(4))) float  f32x4;
typedef __attribute__((ext_vector_type(4))) short  short4v;

// ws layout
#define CNT_OFF   0                        // int cnt[8*16] (64B-padded)
#define HIST_OFF  512                      // int hist[32][8]   (1KB)
#define MAP_OFF   1536                     // int map[520]      (2.08KB)
#define LISTS_OFF 4096                     // int lists[8][8192]
#define W_OFF     (LISTS_OFF + NGRP * BATCH * 4)
#define CNT_STRIDE 16

static __device__ __forceinline__ short bf(float f) {
    __hip_bfloat16 h = __float2bfloat16(f);
    return (short)__bfloat16_as_ushort(h);
}

// Phase 0 (fused): blocks < 1024 repack W (f32 [g][c][k] -> bf16 Wb2
// [g][kk][c][j]): per-MFMA B-load = 1KB contiguous (Wall-B fix, r15-proven).
// Blocks >= 1024: per-block group histogram of `chosen` (LDS atomics).
__global__ __launch_bounds__(256) void init_hist_kernel(
    const float* __restrict__ W,
    const int* __restrict__ chosen,
    unsigned short* __restrict__ Wb2,
    int* __restrict__ hist)
{
    int blk = blockIdx.x;
    int tid = threadIdx.x;
    if (blk < 1024) {
        int e = (blk * 256 + tid) * 4;
        int g = e >> 17;
        int rem = e & ((MAXGS * DMODEL) - 1);
        int c = rem >> 11;
        int k = rem & (DMODEL - 1);
        int kk = k >> 5, j = k & 31;
        float4 w = *reinterpret_cast<const float4*>(W + e);
        ushort4 o;
        o.x = (unsigned short)bf(w.x); o.y = (unsigned short)bf(w.y);
        o.z = (unsigned short)bf(w.z); o.w = (unsigned short)bf(w.w);
        size_t dst = (((size_t)g * NKK + kk) * MAXGS + c) * 32 + j;
        *reinterpret_cast<ushort4*>(Wb2 + dst) = o;
    } else {
        int hb = blk - 1024;               // 0..31
        __shared__ int h[NGRP];
        if (tid < NGRP) h[tid] = 0;
        __syncthreads();
        int g = chosen[hb * 256 + tid];
        atomicAdd(&h[g], 1);               // LDS atomic
        __syncthreads();
        if (tid < NGRP) hist[hb * NGRP + tid] = h[tid];
    }
}

// Phase 1: scan fused into scatter (deterministic ascending-b ballot ranks).
// Block 0 also builds the TILE DIRECTORY map[pos] = (g<<16)|t (t-major,
// g-minor: 8-group XCD rotation + same-t cohorts adjacent).
// r18 BUG FIX: compaction loop now covers t up to 511 (was 63 -- groups with
// cnt > 1024 lost tiles t>=64 -> zero outputs, absmax 1.95); sentinel fill
// now covers all MAXTILES entries.
__global__ __launch_bounds__(256) void scatter_kernel(const int* __restrict__ chosen,
                                                      const int* __restrict__ hist,
                                                      int* __restrict__ lists,
                                                      int* __restrict__ cnt,
                                                      int* __restrict__ map) {
    __shared__ int hloc[NBLK * NGRP];
    __shared__ int gbase[NGRP];
    __shared__ int ntl[NGRP];
    __shared__ int wcnt[4][NGRP];
    __shared__ int wbase[4][NGRP];
    int tid  = threadIdx.x;
    int blk  = blockIdx.x;
    int w    = tid >> 6;
    int lane = tid & 63;

    if (tid < NBLK * NGRP) hloc[tid] = hist[tid];
    __syncthreads();
    if (tid < NGRP) {
        int s = 0;
        for (int b2 = 0; b2 < blk; ++b2) s += hloc[b2 * NGRP + tid];
        gbase[tid] = s;
        int tot = s;
        for (int b2 = blk; b2 < NBLK; ++b2) tot += hloc[b2 * NGRP + tid];
        ntl[tid] = (tot + TM - 1) / TM;
        if (blk == 0) cnt[tid * CNT_STRIDE] = tot;
    }
    __syncthreads();

    if (blk == 0) {
        for (int q = tid; q < MAXTILES; q += 256) map[q] = -1;   // full sentinel
        __syncthreads();
        // t must cover up to 511 (a group can own up to 512 tiles)
        for (int p = tid; p < NGRP * 512; p += 256) {
            int t = p >> 3, gg = p & 7;
            if (t < ntl[gg]) {
                int pos = 0;
                #pragma unroll
                for (int g2 = 0; g2 < NGRP; ++g2) {
                    int nt = ntl[g2];
                    pos += (t < nt ? t : nt);
                    pos += (g2 < gg && nt > t) ? 1 : 0;
                }
                map[pos] = (gg << 16) | t;
            }
        }
    }

    int b = blk * 256 + tid;
    int g = chosen[b];
    int rank = 0;
    unsigned long long below = (1ull << lane) - 1ull;
    #pragma unroll
    for (int gg = 0; gg < NGRP; ++gg) {
        unsigned long long m = __ballot(g == gg);
        if (g == gg) rank = __popcll(m & below);
        if (lane == gg) wcnt[w][gg] = __popcll(m);
    }
    __syncthreads();
    if (tid < NGRP) {
        int base = gbase[tid];
        #pragma unroll
        for (int ww = 0; ww < 4; ++ww) {
            wbase[ww][tid] = base;
            base += wcnt[ww][tid];
        }
    }
    __syncthreads();
    lists[g * BATCH + wbase[w][g] + rank] = b;
}

// Phase 2: serial burst-stage + compute gemm (r15 body, tile-directory grid).
// Stage: each 8KB A-row = 8 back-to-back 1KB loads (~5.8 TB/s), cvt bf16,
// swizzled ds_write. Compute: coalesced B (1KB contiguous per wave-load).
__global__ __launch_bounds__(256, 2) void gemm_kernel(
    const float* __restrict__ hidden,
    const float* __restrict__ bias,
    const int* __restrict__ gsizes,
    const int* __restrict__ cnt,
    const int* __restrict__ lists,
    const int* __restrict__ map,
    const unsigned short* __restrict__ Wb2,
    float* __restrict__ out)
{
    int e = map[blockIdx.x];
    if (e < 0) return;             // sentinel (<=8 of these)
    int g = e >> 16;
    int t = e & 0xFFFF;
    int c = cnt[g * CNT_STRIDE];
    int m0 = t * TM;

    __shared__ unsigned short A[TM][DMODEL];   // bf16, 64 KB

    int tid  = threadIdx.x;
    int w    = tid >> 6;           // wave 0..3
    int lane = tid & 63;
    int lrow = lane & 15;
    int kg   = lane >> 4;          // 0..3

    // ---- stage: wave w owns rows 4w..4w+3; each row = one 8KB burst ----
    {
        const float* src[4];
        #pragma unroll
        for (int i = 0; i < 4; ++i) {
            int m  = m0 + 4 * w + i;
            int ms = m < c ? m : c - 1;          // tail: dup last row (guarded)
            src[i] = hidden + ((size_t)lists[g * BATCH + ms] * NGRP + g) * DMODEL
                   + lane * 4;
        }
        // 2-row software pipeline: 16KB/wave in flight, bursts back-to-back
        f32x4 ra[8], rb[8];
        #pragma unroll
        for (int h = 0; h < 8; ++h)
            ra[h] = *reinterpret_cast<const f32x4*>(src[0] + h * 256);
        #pragma unroll
        for (int h = 0; h < 8; ++h)
            rb[h] = *reinterpret_cast<const f32x4*>(src[1] + h * 256);

        #pragma unroll
        for (int i = 0; i < 4; ++i) {
            int r = 4 * w + i;
            int swz = ((r & 7) << 4) | ((r & 1) << 6);
            char* abase = (char*)&A[r][0];
            #pragma unroll
            for (int h = 0; h < 8; ++h) {
                f32x4 v = ra[h];
                short4v o;
                o[0] = bf(v[0]); o[1] = bf(v[1]); o[2] = bf(v[2]); o[3] = bf(v[3]);
                int byte = (h * 512 + lane * 8) ^ swz;
                *reinterpret_cast<short4v*>(abase + byte) = o;
            }
            if (i < 3) {
                #pragma unroll
                for (int h = 0; h < 8; ++h) ra[h] = rb[h];
                if (i < 2) {
                    #pragma unroll
                    for (int h = 0; h < 8; ++h)
                        rb[h] = *reinterpret_cast<const f32x4*>(src[i + 2] + h * 256);
                }
            }
        }
    }
    __syncthreads();

    // ---- compute: wave w owns cols [16w,16w+16), full K from LDS A ----
    {
        int swzr = ((lrow & 7) << 4) | ((lrow & 1) << 6);
        const char* arow = (const char*)&A[lrow][0];
        const unsigned short* bp =
            Wb2 + (size_t)g * NKK * MAXGS * 32 + (w * 16 + lrow) * 32 + kg * 8;

        f32x4 acc = f32x4{0, 0, 0, 0};
        #pragma unroll 8
        for (int kk = 0; kk < NKK; ++kk) {
            int byte = (kk * 64 + kg * 16) ^ swzr;
            short8 af  = *reinterpret_cast<const short8*>(arow + byte);
            short8 bfr = *reinterpret_cast<const short8*>(bp + (size_t)kk * MAXGS * 32);
            acc = __builtin_amdgcn_mfma_f32_16x16x32_bf16(af, bfr, acc, 0, 0, 0);
        }

        // epilogue: C col = lrow (n within group), row = kg*4 + r
        int gsz = gsizes[g];
        int n = w * 16 + lrow;
        float bv = bias[g * MAXGS + n];
        #pragma unroll
        for (int r = 0; r < 4; ++r) {
            int m = m0 + kg * 4 + r;
            if (m < c) {
                int s = lists[g * BATCH + m];
                out[(size_t)s * MAXGS + n] = acc[r] + bv;   // padded n: 0+0 == 0
                out[(size_t)(BATCH + s) * MAXGS + n] = (n < gsz) ? 1.0f : 0.0f;
            }
        }
    }
}

extern "C" void kernel_launch(void* const* d_in, const int* in_sizes, int n_in,
                              void* d_out, int out_size, void* d_ws, size_t ws_size,
                              hipStream_t stream) {
    const float* hidden = (const float*)d_in[0];   // [8192, 8, 2048] f32
    const int*   chosen = (const int*)d_in[1];     // [8192] i32
    const float* W      = (const float*)d_in[2];   // [8, 64, 2048] f32 (zero-padded)
    const float* bias   = (const float*)d_in[3];   // [8, 64] f32 (zero-padded)
    const int*   gs     = (const int*)d_in[4];     // [8] i32
    float* out = (float*)d_out;                    // [8192*64 preds | 8192*64 valid]

    char* ws = (char*)d_ws;
    int* cnt   = (int*)(ws + CNT_OFF);
    int* hist  = (int*)(ws + HIST_OFF);
    int* map   = (int*)(ws + MAP_OFF);
    int* lists = (int*)(ws + LISTS_OFF);
    unsigned short* Wb2 = (unsigned short*)(ws + W_OFF);

    init_hist_kernel<<<dim3(1024 + NBLK), dim3(256), 0, stream>>>(W, chosen, Wb2, hist);
    scatter_kernel<<<dim3(NBLK), dim3(256), 0, stream>>>(chosen, hist, lists, cnt, map);
    gemm_kernel<<<dim3(MAXTILES), dim3(256), 0, stream>>>(
        hidden, bias, gs, cnt, lists, map, Wb2, out);
}